// Round 14
// baseline (262.720 us; speedup 1.0000x reference)
//
#include <hip/hip_runtime.h>
#include <hip/hip_bf16.h>
#include <math.h>

#define Bn 4096
#define Dd 768
#define SC2 28.85390081777927f   // 20 * log2(e): logits kept in base-2 domain
#define EPSF 1e-6f
#define DG 4.8516519541e8f       // expf(20.0f): exact exp_ori diagonal

// ws layout (4-byte elements)
#define O_S      0        // 3*4096 row sums (ori_nodiag, gen, aug)
#define O_SMOA   12288    // same-masked (ori_nodiag + aug) sums
#define O_SMG    16384    // same-masked gen sums
#define ZERO_F   20480    // floats to zero (covers all atomic sums)
#define O_P      20480    // uint: total pairs (= sum cnt^2)
#define O_RM     20608    // uint2[4096]: {tg | rank<<8, rowSlotBase}
#define LIST_OFF   262144      // byte offset: LCAP uint4 pair entries {row,x0,x1,x2}
#define LCAP       (1u << 19)
#define NB_OFF     33554432    // byte offset: bf16 normalized rows on|gn|an

typedef __attribute__((ext_vector_type(8))) short sh8;
typedef __attribute__((ext_vector_type(4))) float f32x4;

#define AS1 __attribute__((address_space(1)))
#define AS3 __attribute__((address_space(3)))

static __device__ __forceinline__ void gl_lds16(const void* g, void* l) {
    __builtin_amdgcn_global_load_lds((const AS1 void*)g, (AS3 void*)l, 16, 0, 0);
}

static __device__ __forceinline__ unsigned short f2b(float f) {
    unsigned int u = __float_as_uint(f);
    unsigned int r = (u + 0x7fffu + ((u >> 16) & 1u)) >> 16;  // RNE
    return (unsigned short)r;
}

// ---- normalize rows (blocks x<4096) + class sort (block x==4096,y==0) ----
__global__ void norm_sort_kernel(const float* f0, const float* f1, const float* f2,
                                 unsigned short* nb, const int* tg, unsigned int* I,
                                 float* out) {
    int r = blockIdx.x, m = blockIdx.y, tid = threadIdx.x;
    if (r == Bn) {
        if (m != 0) return;
        // ---- sort body (256 threads) ----
        float* F = (float*)I;
        __shared__ unsigned int h[128], pb[128], cur[128];
        for (int e = tid; e < ZERO_F; e += 256) F[e] = 0.f;
        if (tid == 0) { out[0] = 0.f; out[1] = 0.f; }
        if (tid < 128) { h[tid] = 0; cur[tid] = 0; }
        __syncthreads();
        for (int e = tid; e < Bn; e += 256) atomicAdd(&h[tg[e]], 1u);
        __syncthreads();
        if (tid < 128) pb[tid] = h[tid] * h[tid];
        __syncthreads();
        for (int s = 1; s < 128; s <<= 1) {
            unsigned int b = 0;
            if (tid < 128 && tid >= s) b = pb[tid - s];
            __syncthreads();
            if (tid < 128) pb[tid] += b;
            __syncthreads();
        }
        if (tid == 127) I[O_P] = pb[127];
        uint2* RM = (uint2*)(I + O_RM);
        for (int e = tid; e < Bn; e += 256) {
            int c = tg[e];
            unsigned int rk = atomicAdd(&cur[c], 1u);
            unsigned int n = h[c];
            RM[e] = make_uint2((unsigned)c | (rk << 8), (pb[c] - n * n) + rk * n);
        }
        return;
    }
    const float* src = (m == 0 ? f0 : (m == 1 ? f1 : f2)) + (size_t)r * Dd;
    float x0 = src[tid], x1 = src[tid + 256], x2 = src[tid + 512];
    float v = x0 * x0 + x1 * x1 + x2 * x2;
    #pragma unroll
    for (int off = 1; off < 64; off <<= 1) v += __shfl_xor(v, off);
    __shared__ float wr[4];
    if ((tid & 63) == 0) wr[tid >> 6] = v;
    __syncthreads();
    float inv = rsqrtf(wr[0] + wr[1] + wr[2] + wr[3]);
    unsigned short* dst = nb + ((size_t)m * Bn + r) * Dd;
    dst[tid] = f2b(x0 * inv);
    dst[tid + 256] = f2b(x1 * inv);
    dst[tid + 512] = f2b(x2 * inv);
}

// ===== R26: z SPLIT ACROSS WAVES — 12 waves, single-z 64-reg acc ==========
// Model correction (R25 post-mortem): one 16x16x32 MFMA = ~19.4 SIMD-cyc
// (1015 FLOP/cyc/SIMD peak); R23's 2800cy/kt reconciles as 931cy MFMA/wave
// x ~1.65 waves/SIMD = 28% duty. The wall is the 320-reg wave (192 AGPR
// acc for 3z) capping residency at 1.65 waves/SIMD — NOT barriers (R20),
// NOT LDS pipe, NOT L2 (R19 FETCH=ideal). R21/R22 shrank the tile but kept
// 3z/wave (ratio+spill disasters). Untried cell: keep 64x64 wave tiles,
// give each wave ONE z. Block 128x128, 768 thr, 12 waves = 3 z-quads of
// 2x2. acc=64 regs, ~130-150 total (R0 precedent: VGPR_Count 64) ->
// 3 waves/SIMD. A still staged once per block (fusion's FETCH win kept);
// LDS reads/CU-kt drop 128->96 (each wave reads A + only ITS z's B).
// Frozen: R19 skeleton (single 32KB buffer, 2 syncthreads/kt), n-owned
// XCD map, chunk^((row>>1)&3) swizzle, z-indexed epilogue (pre-R16 form).
__launch_bounds__(768, 2)
__global__ void gemm_rowsum(const unsigned short* nb, char* ws) {
    float* F = (float*)ws;
    const unsigned int* I = (const unsigned int*)ws;
    const uint2* RM = (const uint2*)(I + O_RM);
    int bid = blockIdx.x;
    int xcd = bid & 7, local = bid >> 3;                // 8 XCDs x 128 tiles
    int n0 = (xcd * 4 + (local & 3)) * 128;             // 4 n-panels/XCD (B L2-resident)
    int m0 = (local >> 2) * 128;                        // n-inner, m-major
    int tid = threadIdx.x, lane = tid & 63, wave = tid >> 6;   // wave 0..11
    int z = wave >> 2, sub = wave & 3;                  // z-quad of 2x2 waves
    int wm = (sub >> 1) * 64, wn = (sub & 1) * 64;
    int lid = lane & 15, q = lane >> 4;
    __shared__ __align__(16) unsigned short L[4][4096];  // A,B0,B1,B2 = 32 KB

    // staging (tid<512 = waves 0..7): row0 = tid>>2 in [0,128), ch = tid&3.
    // One gl_lds per region per thread covers the full 8 KB region.
    // LDS linear dest, source chunk pre-swizzled (both-sides-or-neither).
    int row0 = tid >> 2, ch = tid & 3;
    int cs = (ch ^ ((row0 >> 1) & 3)) * 8;
    const unsigned short* gA  = nb + (size_t)(m0 + row0) * Dd + cs;
    const unsigned short* gB0 = nb + (size_t)(n0 + row0) * Dd + cs;
    const unsigned short* gB1 = gB0 + (size_t)Bn * Dd;
    const unsigned short* gB2 = gB1 + (size_t)Bn * Dd;

    // frag-read swizzle: r = base + i*16 + lid -> (r>>1)&3 == (lid>>1)&3
    int cswz = (q ^ ((lid >> 1) & 3)) * 8;
    const unsigned short* Bz = &L[1 + z][0];

    f32x4 acc[4][4] = {};   // 64 regs (single z)

    for (int kt = 0; kt < 24; ++kt) {
        __syncthreads();          // prev tile fully consumed
        if (tid < 512) {
            int ko = kt * 32;
            gl_lds16(gA  + ko, &L[0][tid * 8]);
            gl_lds16(gB0 + ko, &L[1][tid * 8]);
            gl_lds16(gB1 + ko, &L[2][tid * 8]);
            gl_lds16(gB2 + ko, &L[3][tid * 8]);
        }
        __syncthreads();          // publish (vmcnt+lgkm drained)
        sh8 af[4], bf[4];
        #pragma unroll
        for (int i = 0; i < 4; ++i)
            af[i] = *(const sh8*)&L[0][(wm + i * 16 + lid) * 32 + cswz];
        #pragma unroll
        for (int j = 0; j < 4; ++j)
            bf[j] = *(const sh8*)&Bz[(wn + j * 16 + lid) * 32 + cswz];
        __builtin_amdgcn_s_setprio(1);
        #pragma unroll
        for (int i = 0; i < 4; ++i)
            #pragma unroll
            for (int j = 0; j < 4; ++j)
                acc[i][j] = __builtin_amdgcn_mfma_f32_16x16x32_bf16(af[i], bf[j], acc[i][j], 0, 0, 0);
        __builtin_amdgcn_s_setprio(0);
    }

    // ---- z-indexed epilogue (pre-R16 proven form): row sum, masked sum,
    // per-z pair-list word stores ----
    uint2 rmc[4];
    #pragma unroll
    for (int j = 0; j < 4; ++j) rmc[j] = RM[n0 + wn + j * 16 + lid];
    int smoff = (z == 1) ? O_SMG : O_SMOA;
    unsigned int* Lw = (unsigned int*)(ws + LIST_OFF);
    #pragma unroll
    for (int i = 0; i < 4; ++i)
        #pragma unroll
        for (int reg = 0; reg < 4; ++reg) {
            int grow = m0 + wm + i * 16 + q * 4 + reg;
            uint2 rm = RM[grow];
            unsigned int trow = rm.x & 255u, rsb = rm.y;
            float rs = 0.f, ms = 0.f;
            #pragma unroll
            for (int j = 0; j < 4; ++j) {
                int gcol = n0 + wn + j * 16 + lid;
                float x = acc[i][j][reg] * SC2;
                float e = exp2f(x);
                if (z == 0 && gcol == grow) e = 0.f;   // ori diagonal excluded
                rs += e;
                if ((rmc[j].x & 255u) == trow) {
                    ms += e;
                    unsigned int slot = rsb + (rmc[j].x >> 8);
                    if (slot < LCAP) {
                        if (z == 0) {
                            Lw[slot * 4 + 0] = (unsigned)grow;
                            Lw[slot * 4 + 1] = __float_as_uint(x);
                        } else {
                            Lw[slot * 4 + 1 + z] = __float_as_uint(x);
                        }
                    }
                }
            }
            #pragma unroll
            for (int off = 1; off < 16; off <<= 1) {
                rs += __shfl_xor(rs, off);
                ms += __shfl_xor(ms, off);
            }
            if (lid == 0) {
                atomicAdd(&F[O_S + z * Bn + grow], rs);
                atomicAdd(&F[smoff + grow], ms);
            }
        }
}

// ---- flat loss pass: inline denominators, scaled atomic into d_out ----
__launch_bounds__(256)
__global__ void loss_kernel(char* ws, float* out) {
    float* F = (float*)ws;
    const unsigned int* I = (const unsigned int*)ws;
    const uint4* L = (const uint4*)(ws + LIST_OFF);
    unsigned int n = I[O_P]; if (n > LCAP) n = LCAP;
    float a0 = 0.f, a1 = 0.f;
    unsigned int stride = gridDim.x * 256;
    for (unsigned int idx = blockIdx.x * 256 + threadIdx.x; idx < n; idx += stride) {
        uint4 en = L[idx];
        int i = (int)en.x;
        float son = F[O_S + i], sgen = F[O_S + Bn + i], saug = F[O_S + 2 * Bn + i];
        float dco = (son + saug - F[O_SMOA + i]) + sgen + EPSF;
        float dad = (sgen - F[O_SMG + i]) + saug + son + DG + EPSF;
        float eo = exp2f(__uint_as_float(en.y));
        float eg = exp2f(__uint_as_float(en.z));
        float ea = exp2f(__uint_as_float(en.w));
        a0 += -__logf(eg / (eg + dad) + EPSF);
        a1 += -__logf(eo / (eo + dco) + EPSF) - __logf(ea / (ea + dco) + EPSF);
    }
    #pragma unroll
    for (int off = 1; off < 64; off <<= 1) { a0 += __shfl_xor(a0, off); a1 += __shfl_xor(a1, off); }
    __shared__ float r0[4], r1[4];
    int tid = threadIdx.x;
    if ((tid & 63) == 0) { r0[tid >> 6] = a0; r1[tid >> 6] = a1; }
    __syncthreads();
    if (tid == 0) {
        atomicAdd(&out[0], (r0[0] + r0[1] + r0[2] + r0[3]) * (1.0f / Bn));  // ad_loss
        atomicAdd(&out[1], (r1[0] + r1[1] + r1[2] + r1[3]) * (1.0f / Bn));  // co_loss
    }
}

extern "C" void kernel_launch(void* const* d_in, const int* in_sizes, int n_in,
                              void* d_out, int out_size, void* d_ws, size_t ws_size,
                              hipStream_t stream) {
    const float* f0 = (const float*)d_in[0];
    const float* f1 = (const float*)d_in[1];
    const float* f2 = (const float*)d_in[2];
    const int* tg = (const int*)d_in[3];
    char* ws = (char*)d_ws;
    unsigned int* I = (unsigned int*)d_ws;
    unsigned short* nb = (unsigned short*)(ws + NB_OFF);
    float* out = (float*)d_out;

    norm_sort_kernel<<<dim3(Bn + 1, 3), 256, 0, stream>>>(f0, f1, f2, nb, tg, I, out);
    gemm_rowsum<<<dim3(1024), 768, 0, stream>>>(nb, ws);
    loss_kernel<<<256, 256, 0, stream>>>(ws, out);
}